// Round 8
// baseline (286.623 us; speedup 1.0000x reference)
//
#include <hip/hip_runtime.h>
#include <math.h>

typedef unsigned short u16;
typedef unsigned int   u32;

#define B_   16
#define C_   256
#define HW_  1024
#define N_   16384      // B*H*W rows
#define NE_  8192       // codebook entries
#define K_   256        // feature dim
#define NSPLIT 8
#define CPS  1024       // codes per split
#define NZQ  4194304    // B*C*H*W

typedef _Float16 f16x8 __attribute__((ext_vector_type(8)));
typedef float    f32x16 __attribute__((ext_vector_type(16)));

// output layout: [0, NZQ) = z_q (B,C,H,W); [NZQ] = loss; [NZQ+1, NZQ+1+N_) = indices (as float)

__device__ __forceinline__ u16 f2h(float x) {
    union { _Float16 h; u16 u; } c;
    c.h = (_Float16)x;
    return c.u;
}

// ---------------------------------------------------------------------------
// A: transpose z (B,C,HW) -> z_flat [N_, K_] fp32 + fp16
__global__ void k_transpose_z(const float* __restrict__ z, float* __restrict__ zf,
                              u16* __restrict__ zh) {
    __shared__ float tile[32][33];
    int b   = blockIdx.z;
    int hw0 = blockIdx.x * 32;
    int c0  = blockIdx.y * 32;
    int tx = threadIdx.x;   // 0..31
    int ty = threadIdx.y;   // 0..7
    #pragma unroll
    for (int i = 0; i < 4; ++i) {
        int c = c0 + ty + i * 8;
        tile[ty + i * 8][tx] = z[((size_t)b * C_ + c) * HW_ + hw0 + tx];
    }
    __syncthreads();
    #pragma unroll
    for (int i = 0; i < 4; ++i) {
        int hw = hw0 + ty + i * 8;
        size_t o = ((size_t)b * HW_ + hw) * C_ + c0 + tx;
        float v = tile[tx][ty + i * 8];
        zf[o] = v;
        zh[o] = f2h(v);
    }
}

// ---------------------------------------------------------------------------
// B: codebook GEMM: cb[n][c] = sum_d frozen[n][d] * w[c][d]; also fp16 copy
__global__ __launch_bounds__(256) void k_codebook_gemm(
        const float* __restrict__ f, const float* __restrict__ w,
        float* __restrict__ cb, u16* __restrict__ cbh) {
    __shared__ float Fs[16][68];
    __shared__ float Ws[16][68];
    int n0 = blockIdx.x * 64;
    int c0 = blockIdx.y * 64;
    int tid = threadIdx.x;
    int tx = tid & 15, ty = tid >> 4;
    int nl = tid >> 2;            // 0..63
    int kq = (tid & 3) * 4;       // 0,4,8,12
    float acc[4][4] = {};
    for (int kb = 0; kb < K_; kb += 16) {
        float4 fv = *(const float4*)&f[(size_t)(n0 + nl) * K_ + kb + kq];
        float4 wv = *(const float4*)&w[(size_t)(c0 + nl) * K_ + kb + kq];
        __syncthreads();
        Fs[kq + 0][nl] = fv.x; Fs[kq + 1][nl] = fv.y; Fs[kq + 2][nl] = fv.z; Fs[kq + 3][nl] = fv.w;
        Ws[kq + 0][nl] = wv.x; Ws[kq + 1][nl] = wv.y; Ws[kq + 2][nl] = wv.z; Ws[kq + 3][nl] = wv.w;
        __syncthreads();
        #pragma unroll
        for (int k = 0; k < 16; ++k) {
            float4 a = *(float4*)&Fs[k][ty * 4];
            float4 b = *(float4*)&Ws[k][tx * 4];
            float av[4] = {a.x, a.y, a.z, a.w};
            float bv[4] = {b.x, b.y, b.z, b.w};
            #pragma unroll
            for (int i = 0; i < 4; ++i)
                #pragma unroll
                for (int j = 0; j < 4; ++j)
                    acc[i][j] += av[i] * bv[j];
        }
    }
    #pragma unroll
    for (int i = 0; i < 4; ++i) {
        size_t o = (size_t)(n0 + ty * 4 + i) * K_ + c0 + tx * 4;
        *(float4*)&cb[o] = make_float4(acc[i][0], acc[i][1], acc[i][2], acc[i][3]);
        *(ushort4*)&cbh[o] = make_ushort4(f2h(acc[i][0]), f2h(acc[i][1]),
                                          f2h(acc[i][2]), f2h(acc[i][3]));
    }
}

// ---------------------------------------------------------------------------
// B2: c2[n] = ||cb[n]||^2 (fp32 for scan) and fp64 (for exact rescore)
__global__ void k_c2(const float* __restrict__ cb, float* __restrict__ c2,
                     double* __restrict__ c2d) {
    int row  = blockIdx.x * 4 + (threadIdx.x >> 6);
    int lane = threadIdx.x & 63;
    float4 v = *(const float4*)&cb[(size_t)row * K_ + lane * 4];
    double s = (double)v.x * v.x + (double)v.y * v.y
             + (double)v.z * v.z + (double)v.w * v.w;
    #pragma unroll
    for (int off = 32; off; off >>= 1) s += __shfl_down(s, off, 64);
    if (lane == 0) { c2d[row] = s; c2[row] = (float)s; }
}

// ---------------------------------------------------------------------------
// C: single-product fp16 MFMA distance scan. score = ||c||^2 - 2 z.c
// Block: 128 codes x 256 z-rows; each wave handles ALL 128 codes x 64 z-rows
// (acc = 8 f32x16 tiles = 128 AGPR) -> 6 ds_read per 8 MFMA (was 8 per 4),
// 2.7x less LDS traffic per FLOP; no cross-wave merge (each z-row owned by
// one wave). fp16 noise ~4e-4 << within-split top spacing; top-2/split kept,
// all 16 candidates fp64-rescored in finalize.
// NOTE: __launch_bounds__(256,2); (256,4) spills the accumulator (r4).
__device__ __forceinline__ void ld_lds16(const void* g, void* l) {
    __builtin_amdgcn_global_load_lds((const __attribute__((address_space(1))) void*)g,
                                     (__attribute__((address_space(3))) void*)l, 16, 0, 0);
}

__global__ __launch_bounds__(256, 2) void k_scan_mfma(
        const u16* __restrict__ zh, const u16* __restrict__ cbh,
        const float* __restrict__ c2, int* __restrict__ t2i) {
    __shared__ __align__(16) u16 sA[8192];    // 128 codes x 64 k, xor-swizzled 16B units
    __shared__ __align__(16) u16 sB[16384];   // 256 zrows x 64 k
    __shared__ float c2s[128];

    int r0    = blockIdx.x * 256;
    int split = blockIdx.y;
    int tid  = threadIdx.x;
    int wave = tid >> 6, lane = tid & 63;
    int l31 = lane & 31, q = lane >> 5;

    // running top-2 per lane per j (z-row = r0 + wave*64 + j*32 + l31)
    float rs1[2] = {1e30f, 1e30f}, rs2[2] = {1e30f, 1e30f};
    int   ri1[2] = {0, 0},         ri2[2] = {0, 0};

    for (int ct = 0; ct < CPS / 128; ++ct) {
        int code0 = split * CPS + ct * 128;
        f32x16 acc[4][2];
        #pragma unroll
        for (int i = 0; i < 4; ++i)
            #pragma unroll
            for (int j = 0; j < 2; ++j)
                acc[i][j] = (f32x16){};
        for (int kb = 0; kb < K_; kb += 64) {
            const u16* Ab = cbh + (size_t)code0 * K_ + kb;
            const u16* Bb = zh  + (size_t)r0 * K_ + kb;
            __syncthreads();
            #pragma unroll
            for (int it = 0; it < 8; ++it) {
                int S = (it * 4 + wave) * 64 + lane;
                int row = S >> 3, u = S & 7;
                int k8 = (u ^ (row & 7)) * 8;
                size_t goff = (size_t)row * K_ + k8;
                u32 loff = (u32)(it * 4 + wave) * 512;
                if (it < 4) ld_lds16(Ab + goff, &sA[loff]);
                ld_lds16(Bb + goff, &sB[loff]);
            }
            if (kb == 0 && tid < 128) c2s[tid] = c2[code0 + tid];
            __syncthreads();
            #pragma unroll
            for (int ks = 0; ks < 4; ++ks) {
                f16x8 af[4], bf[2];
                #pragma unroll
                for (int i = 0; i < 4; ++i) {
                    int rowa = i * 32 + l31;
                    u32 ao = (u32)(rowa * 8 + ((ks * 2 + q) ^ (rowa & 7))) * 8;
                    af[i] = *(const f16x8*)&sA[ao];
                }
                #pragma unroll
                for (int j = 0; j < 2; ++j) {
                    int rowb = wave * 64 + j * 32 + l31;
                    u32 bo = (u32)(rowb * 8 + ((ks * 2 + q) ^ (rowb & 7))) * 8;
                    bf[j] = *(const f16x8*)&sB[bo];
                }
                #pragma unroll
                for (int i = 0; i < 4; ++i)
                    #pragma unroll
                    for (int j = 0; j < 2; ++j)
                        acc[i][j] = __builtin_amdgcn_mfma_f32_32x32x16_f16(af[i], bf[j], acc[i][j], 0, 0, 0);
            }
        }
        // epilogue: scores for this 128-code tile, insert into running top-2
        #pragma unroll
        for (int i = 0; i < 4; ++i) {
            float c2r[16];
            #pragma unroll
            for (int h = 0; h < 4; ++h) {
                float4 v = *(float4*)&c2s[i * 32 + 4 * q + 8 * h];
                c2r[h * 4 + 0] = v.x; c2r[h * 4 + 1] = v.y;
                c2r[h * 4 + 2] = v.z; c2r[h * 4 + 3] = v.w;
            }
            int ibase = code0 + i * 32 + 4 * q;
            #pragma unroll
            for (int j = 0; j < 2; ++j) {
                const f32x16& a = acc[i][j];
                #pragma unroll
                for (int r = 0; r < 16; ++r) {
                    float s = c2r[r] - 2.0f * a[r];
                    int idx = ibase + (r & 3) + 8 * (r >> 2);
                    if (s < rs1[j])      { rs2[j] = rs1[j]; ri2[j] = ri1[j]; rs1[j] = s; ri1[j] = idx; }
                    else if (s < rs2[j]) { rs2[j] = s; ri2[j] = idx; }
                }
            }
        }
    }
    // merge q-halves (lanes l <-> l^32)
    #pragma unroll
    for (int j = 0; j < 2; ++j) {
        float os1 = __shfl_xor(rs1[j], 32, 64);
        int   oi1 = __shfl_xor(ri1[j], 32, 64);
        float os2 = __shfl_xor(rs2[j], 32, 64);
        int   oi2 = __shfl_xor(ri2[j], 32, 64);
        if (os1 < rs1[j])      { rs2[j] = rs1[j]; ri2[j] = ri1[j]; rs1[j] = os1; ri1[j] = oi1; }
        else if (os1 < rs2[j]) { rs2[j] = os1; ri2[j] = oi1; }
        if (os2 < rs1[j])      { rs2[j] = rs1[j]; ri2[j] = ri1[j]; rs1[j] = os2; ri1[j] = oi2; }
        else if (os2 < rs2[j]) { rs2[j] = os2; ri2[j] = oi2; }
    }
    if (q == 0) {
        #pragma unroll
        for (int j = 0; j < 2; ++j) {
            int n = r0 + wave * 64 + j * 32 + l31;
            size_t o = ((size_t)split * N_ + n) * 2;
            t2i[o] = ri1[j]; t2i[o + 1] = ri2[j];
        }
    }
}

// ---------------------------------------------------------------------------
// D: fp64 rescore of ALL 16 candidates/row fully in-wave (4 lanes/cand),
//    argmin via width-16 shuffle butterfly (index tie-break); gather z_q;
//    loss partials; transposed (B,C,H,W) write. One barrier total.
__global__ __launch_bounds__(256) void k_finalize(
        const float* __restrict__ zf, const float* __restrict__ cb,
        const double* __restrict__ c2d, const int* __restrict__ t2i,
        float* __restrict__ out, float* __restrict__ partials) {
    __shared__ int   bidx[16];
    __shared__ float wsum[4];
    __shared__ float tile[16][260];
    int n0 = blockIdx.x * 16;
    int tid = threadIdx.x;
    int wv = tid >> 6, lane = tid & 63;
    int cand = lane >> 2, t = lane & 3;
    int sp = cand >> 1, wsel = cand & 1;

    for (int rr = 0; rr < 4; ++rr) {
        int n = n0 + wv * 4 + rr;
        int ci = t2i[((size_t)sp * N_ + n) * 2 + wsel];
        double acc = 0.0;
        const float* zp = zf + (size_t)n * K_ + t * 64;
        const float* cp = cb + (size_t)ci * K_ + t * 64;
        #pragma unroll
        for (int j4 = 0; j4 < 16; ++j4) {
            float4 zv = *(const float4*)&zp[j4 * 4];
            float4 cv = *(const float4*)&cp[j4 * 4];
            acc += (double)zv.x * cv.x + (double)zv.y * cv.y
                 + (double)zv.z * cv.z + (double)zv.w * cv.w;
        }
        acc += __shfl_xor(acc, 1, 4);
        acc += __shfl_xor(acc, 2, 4);
        double sc = c2d[ci] - 2.0 * acc;
        // gather the 16 cand scores to lanes 0..15, then min-butterfly
        double sg = __shfl(sc, 4 * (lane & 15), 64);
        int    ig = __shfl(ci, 4 * (lane & 15), 64);
        #pragma unroll
        for (int off = 1; off < 16; off <<= 1) {
            double os = __shfl_xor(sg, off, 16);
            int    oi = __shfl_xor(ig, off, 16);
            if (os < sg || (os == sg && oi < ig)) { sg = os; ig = oi; }
        }
        if (lane == 0) {
            bidx[wv * 4 + rr] = ig;
            out[(size_t)NZQ + 1 + n] = (float)ig;   // indices output
        }
    }
    __syncthreads();

    // phase 2: gather + squared-error partial + stage for transposed write
    float accl = 0.f;
    for (int l = 0; l < 16; ++l) {
        int n = n0 + l;
        int bi = bidx[l];
        float zq = cb[(size_t)bi * K_ + tid];
        float d  = zf[(size_t)n * K_ + tid] - zq;
        accl += d * d;
        tile[l][tid] = zq;
    }
    #pragma unroll
    for (int off = 32; off; off >>= 1) accl += __shfl_down(accl, off, 64);
    if ((tid & 63) == 0) wsum[tid >> 6] = accl;
    __syncthreads();
    if (tid == 0) partials[blockIdx.x] = wsum[0] + wsum[1] + wsum[2] + wsum[3];
    // transposed write: out[(b*C + c)*HW + hw0 + l]
    int b = n0 >> 10, hw0 = n0 & 1023;
    #pragma unroll
    for (int g = 0; g < 4; ++g) {
        float4 v = make_float4(tile[g * 4 + 0][tid], tile[g * 4 + 1][tid],
                               tile[g * 4 + 2][tid], tile[g * 4 + 3][tid]);
        *(float4*)&out[((size_t)b * C_ + tid) * HW_ + hw0 + g * 4] = v;
    }
}

// ---------------------------------------------------------------------------
// E: loss = 1.25 * sum(partials) / (N*C)
__global__ void k_loss(const float* __restrict__ partials, float* __restrict__ out) {
    __shared__ double ws4[4];
    int tid = threadIdx.x;
    double s = 0.0;
    for (int i = tid; i < 1024; i += 256) s += (double)partials[i];
    #pragma unroll
    for (int off = 32; off; off >>= 1) s += __shfl_down(s, off, 64);
    if ((tid & 63) == 0) ws4[tid >> 6] = s;
    __syncthreads();
    if (tid == 0) {
        double tot = ws4[0] + ws4[1] + ws4[2] + ws4[3];
        out[NZQ] = (float)(1.25 * tot / (double)NZQ);
    }
}

// ---------------------------------------------------------------------------
extern "C" void kernel_launch(void* const* d_in, const int* in_sizes, int n_in,
                              void* d_out, int out_size, void* d_ws, size_t ws_size,
                              hipStream_t stream) {
    const float* z  = (const float*)d_in[0];
    const float* fc = (const float*)d_in[1];
    const float* wt = (const float*)d_in[2];
    float* out = (float*)d_out;

    float* ws = (float*)d_ws;
    const size_t OFF_ZF   = 0;                                   // N*K f
    const size_t OFF_CB   = OFF_ZF + (size_t)N_ * K_;            // NE*K f
    const size_t OFF_C2   = OFF_CB + (size_t)NE_ * K_;           // NE f
    const size_t OFF_C2D  = OFF_C2 + NE_;                        // NE d (2 f each)
    const size_t OFF_T2I  = OFF_C2D + (size_t)NE_ * 2;           // NSPLIT*N*2 i
    const size_t OFF_PART = OFF_T2I + (size_t)NSPLIT * N_ * 2;   // 1024 f
    const size_t OFF_ZH   = OFF_PART + 1024;                     // fp16 N*K
    const size_t OFF_CBH  = OFF_ZH + (size_t)N_ * K_ / 2;        // fp16 NE*K

    float*  zf   = ws + OFF_ZF;
    float*  cb   = ws + OFF_CB;
    float*  c2   = ws + OFF_C2;
    double* c2d  = (double*)(ws + OFF_C2D);
    int*    t2i  = (int*)(ws + OFF_T2I);
    float*  part = ws + OFF_PART;
    u16*    zh   = (u16*)(ws + OFF_ZH);
    u16*    cbh  = (u16*)(ws + OFF_CBH);

    k_transpose_z<<<dim3(HW_ / 32, C_ / 32, B_), dim3(32, 8), 0, stream>>>(z, zf, zh);
    k_codebook_gemm<<<dim3(NE_ / 64, K_ / 64), 256, 0, stream>>>(fc, wt, cb, cbh);
    k_c2<<<NE_ / 4, 256, 0, stream>>>(cb, c2, c2d);
    k_scan_mfma<<<dim3(N_ / 256, NSPLIT), 256, 0, stream>>>(zh, cbh, c2, t2i);
    k_finalize<<<N_ / 16, 256, 0, stream>>>(zf, cb, c2d, t2i, out, part);
    k_loss<<<1, 256, 0, stream>>>(part, out);
}

// Round 9
// 259.556 us; speedup vs baseline: 1.1043x; 1.1043x over previous
//
#include <hip/hip_runtime.h>
#include <math.h>

typedef unsigned short u16;
typedef unsigned int   u32;

#define B_   16
#define C_   256
#define HW_  1024
#define N_   16384      // B*H*W rows
#define NE_  8192       // codebook entries
#define K_   256        // feature dim
#define NSPLIT 8
#define CPS  1024       // codes per split
#define NZQ  4194304    // B*C*H*W

typedef _Float16 f16x8 __attribute__((ext_vector_type(8)));
typedef float    f32x16 __attribute__((ext_vector_type(16)));

// output layout: [0, NZQ) = z_q (B,C,H,W); [NZQ] = loss; [NZQ+1, NZQ+1+N_) = indices (as float)

__device__ __forceinline__ u16 f2h(float x) {
    union { _Float16 h; u16 u; } c;
    c.h = (_Float16)x;
    return c.u;
}

// ---------------------------------------------------------------------------
// A: transpose z (B,C,HW) -> z_flat [N_, K_] fp32 + fp16
__global__ void k_transpose_z(const float* __restrict__ z, float* __restrict__ zf,
                              u16* __restrict__ zh) {
    __shared__ float tile[32][33];
    int b   = blockIdx.z;
    int hw0 = blockIdx.x * 32;
    int c0  = blockIdx.y * 32;
    int tx = threadIdx.x;   // 0..31
    int ty = threadIdx.y;   // 0..7
    #pragma unroll
    for (int i = 0; i < 4; ++i) {
        int c = c0 + ty + i * 8;
        tile[ty + i * 8][tx] = z[((size_t)b * C_ + c) * HW_ + hw0 + tx];
    }
    __syncthreads();
    #pragma unroll
    for (int i = 0; i < 4; ++i) {
        int hw = hw0 + ty + i * 8;
        size_t o = ((size_t)b * HW_ + hw) * C_ + c0 + tx;
        float v = tile[tx][ty + i * 8];
        zf[o] = v;
        zh[o] = f2h(v);
    }
}

// ---------------------------------------------------------------------------
// B: codebook GEMM: cb[n][c] = sum_d frozen[n][d] * w[c][d]; also fp16 copy
__global__ __launch_bounds__(256) void k_codebook_gemm(
        const float* __restrict__ f, const float* __restrict__ w,
        float* __restrict__ cb, u16* __restrict__ cbh) {
    __shared__ float Fs[16][68];
    __shared__ float Ws[16][68];
    int n0 = blockIdx.x * 64;
    int c0 = blockIdx.y * 64;
    int tid = threadIdx.x;
    int tx = tid & 15, ty = tid >> 4;
    int nl = tid >> 2;            // 0..63
    int kq = (tid & 3) * 4;       // 0,4,8,12
    float acc[4][4] = {};
    for (int kb = 0; kb < K_; kb += 16) {
        float4 fv = *(const float4*)&f[(size_t)(n0 + nl) * K_ + kb + kq];
        float4 wv = *(const float4*)&w[(size_t)(c0 + nl) * K_ + kb + kq];
        __syncthreads();
        Fs[kq + 0][nl] = fv.x; Fs[kq + 1][nl] = fv.y; Fs[kq + 2][nl] = fv.z; Fs[kq + 3][nl] = fv.w;
        Ws[kq + 0][nl] = wv.x; Ws[kq + 1][nl] = wv.y; Ws[kq + 2][nl] = wv.z; Ws[kq + 3][nl] = wv.w;
        __syncthreads();
        #pragma unroll
        for (int k = 0; k < 16; ++k) {
            float4 a = *(float4*)&Fs[k][ty * 4];
            float4 b = *(float4*)&Ws[k][tx * 4];
            float av[4] = {a.x, a.y, a.z, a.w};
            float bv[4] = {b.x, b.y, b.z, b.w};
            #pragma unroll
            for (int i = 0; i < 4; ++i)
                #pragma unroll
                for (int j = 0; j < 4; ++j)
                    acc[i][j] += av[i] * bv[j];
        }
    }
    #pragma unroll
    for (int i = 0; i < 4; ++i) {
        size_t o = (size_t)(n0 + ty * 4 + i) * K_ + c0 + tx * 4;
        *(float4*)&cb[o] = make_float4(acc[i][0], acc[i][1], acc[i][2], acc[i][3]);
        *(ushort4*)&cbh[o] = make_ushort4(f2h(acc[i][0]), f2h(acc[i][1]),
                                          f2h(acc[i][2]), f2h(acc[i][3]));
    }
}

// ---------------------------------------------------------------------------
// B2: c2[n] = ||cb[n]||^2 (fp32 for scan) and fp64 (for exact rescore)
__global__ void k_c2(const float* __restrict__ cb, float* __restrict__ c2,
                     double* __restrict__ c2d) {
    int row  = blockIdx.x * 4 + (threadIdx.x >> 6);
    int lane = threadIdx.x & 63;
    float4 v = *(const float4*)&cb[(size_t)row * K_ + lane * 4];
    double s = (double)v.x * v.x + (double)v.y * v.y
             + (double)v.z * v.z + (double)v.w * v.w;
    #pragma unroll
    for (int off = 32; off; off >>= 1) s += __shfl_down(s, off, 64);
    if (lane == 0) { c2d[row] = s; c2[row] = (float)s; }
}

// ---------------------------------------------------------------------------
// C: single-product fp16 MFMA distance scan. score = ||c||^2 - 2 z.c
// Block: 128 codes x 128 z-rows; each wave: ALL 128 codes x 32 z-rows
// (acc = 4 f32x16 = 64 AGPR). __launch_bounds__(256,3) caps total regs at
// 170 (64 acc + <=106 arch) -> 3 waves/SIMD, 3 blocks/CU (was 2).
// TRIPWIRE: if WRITE_SIZE blows up, the cap spilled -> revert to (256,2).
__device__ __forceinline__ void ld_lds16(const void* g, void* l) {
    __builtin_amdgcn_global_load_lds((const __attribute__((address_space(1))) void*)g,
                                     (__attribute__((address_space(3))) void*)l, 16, 0, 0);
}

__global__ __launch_bounds__(256, 3) void k_scan_mfma(
        const u16* __restrict__ zh, const u16* __restrict__ cbh,
        const float* __restrict__ c2, int* __restrict__ t2i) {
    __shared__ __align__(16) u16 sA[8192];   // 128 codes x 64 k, xor-swizzled 16B units
    __shared__ __align__(16) u16 sB[8192];   // 128 zrows x 64 k
    __shared__ float c2s[128];

    int r0    = blockIdx.x * 128;
    int split = blockIdx.y;
    int tid  = threadIdx.x;
    int wave = tid >> 6, lane = tid & 63;
    int l31 = lane & 31, q = lane >> 5;

    // running top-2 per lane (z-row = r0 + wave*32 + l31; q-halves merged at end)
    float rs1 = 1e30f, rs2 = 1e30f;
    int   ri1 = 0,     ri2 = 0;

    for (int ct = 0; ct < CPS / 128; ++ct) {
        int code0 = split * CPS + ct * 128;
        f32x16 acc[4];
        #pragma unroll
        for (int i = 0; i < 4; ++i) acc[i] = (f32x16){};
        for (int kb = 0; kb < K_; kb += 64) {
            const u16* Ab = cbh + (size_t)code0 * K_ + kb;
            const u16* Bb = zh  + (size_t)r0 * K_ + kb;
            __syncthreads();
            #pragma unroll
            for (int it = 0; it < 4; ++it) {
                int S = (it * 4 + wave) * 64 + lane;
                int row = S >> 3, u = S & 7;
                int k8 = (u ^ (row & 7)) * 8;
                size_t goff = (size_t)row * K_ + k8;
                u32 loff = (u32)(it * 4 + wave) * 512;
                ld_lds16(Ab + goff, &sA[loff]);
                ld_lds16(Bb + goff, &sB[loff]);
            }
            if (kb == 0 && tid < 128) c2s[tid] = c2[code0 + tid];
            __syncthreads();
            #pragma unroll
            for (int ks = 0; ks < 4; ++ks) {
                f16x8 af[4], bf;
                #pragma unroll
                for (int i = 0; i < 4; ++i) {
                    int rowa = i * 32 + l31;
                    u32 ao = (u32)(rowa * 8 + ((ks * 2 + q) ^ (rowa & 7))) * 8;
                    af[i] = *(const f16x8*)&sA[ao];
                }
                {
                    int rowb = wave * 32 + l31;
                    u32 bo = (u32)(rowb * 8 + ((ks * 2 + q) ^ (rowb & 7))) * 8;
                    bf = *(const f16x8*)&sB[bo];
                }
                #pragma unroll
                for (int i = 0; i < 4; ++i)
                    acc[i] = __builtin_amdgcn_mfma_f32_32x32x16_f16(af[i], bf, acc[i], 0, 0, 0);
            }
        }
        // epilogue: scores for this 128-code tile, insert into running top-2
        #pragma unroll
        for (int i = 0; i < 4; ++i) {
            float c2r[16];
            #pragma unroll
            for (int h = 0; h < 4; ++h) {
                float4 v = *(float4*)&c2s[i * 32 + 4 * q + 8 * h];
                c2r[h * 4 + 0] = v.x; c2r[h * 4 + 1] = v.y;
                c2r[h * 4 + 2] = v.z; c2r[h * 4 + 3] = v.w;
            }
            int ibase = code0 + i * 32 + 4 * q;
            const f32x16& a = acc[i];
            #pragma unroll
            for (int r = 0; r < 16; ++r) {
                float s = c2r[r] - 2.0f * a[r];
                int idx = ibase + (r & 3) + 8 * (r >> 2);
                if (s < rs1)      { rs2 = rs1; ri2 = ri1; rs1 = s; ri1 = idx; }
                else if (s < rs2) { rs2 = s; ri2 = idx; }
            }
        }
    }
    // merge q-halves (lanes l <-> l^32)
    {
        float os1 = __shfl_xor(rs1, 32, 64);
        int   oi1 = __shfl_xor(ri1, 32, 64);
        float os2 = __shfl_xor(rs2, 32, 64);
        int   oi2 = __shfl_xor(ri2, 32, 64);
        if (os1 < rs1)      { rs2 = rs1; ri2 = ri1; rs1 = os1; ri1 = oi1; }
        else if (os1 < rs2) { rs2 = os1; ri2 = oi1; }
        if (os2 < rs1)      { rs2 = rs1; ri2 = ri1; rs1 = os2; ri1 = oi2; }
        else if (os2 < rs2) { rs2 = os2; ri2 = oi2; }
    }
    if (q == 0) {
        int n = r0 + wave * 32 + l31;
        size_t o = ((size_t)split * N_ + n) * 2;
        t2i[o] = ri1; t2i[o + 1] = ri2;
    }
}

// ---------------------------------------------------------------------------
// D: fp64 rescore of ALL 16 candidates/row. One wave per row (4 rows/wave
// serial); per candidate-pair the two 32-lane halves each read one cb row
// fully coalesced, butterfly-reduce, exchange via shfl_xor(32), ordered
// running-min with index tie-break. One barrier total.
__global__ __launch_bounds__(256) void k_finalize(
        const float* __restrict__ zf, const float* __restrict__ cb,
        const double* __restrict__ c2d, const int* __restrict__ t2i,
        float* __restrict__ out, float* __restrict__ partials) {
    __shared__ int   bidx[16];
    __shared__ float wsum[4];
    __shared__ float tile[16][260];
    int n0 = blockIdx.x * 16;
    int tid = threadIdx.x;
    int wv = tid >> 6, lane = tid & 63;
    int h = lane >> 5, l5 = lane & 31;

    for (int rr = 0; rr < 4; ++rr) {
        int n = n0 + wv * 4 + rr;
        double bs = 1e300; int bi = 0x7fffffff;
        for (int p = 0; p < 8; ++p) {
            int t = 2 * p + h;                 // candidate id 0..15
            int sp = t >> 1, wsel = t & 1;
            int ci = t2i[((size_t)sp * N_ + n) * 2 + wsel];
            double acc = 0.0;
            const float* zp = zf + (size_t)n * K_;
            const float* cp = cb + (size_t)ci * K_;
            #pragma unroll
            for (int jj = 0; jj < 2; ++jj) {
                float4 zv = *(const float4*)&zp[l5 * 4 + jj * 128];
                float4 cv = *(const float4*)&cp[l5 * 4 + jj * 128];
                acc += (double)zv.x * cv.x + (double)zv.y * cv.y
                     + (double)zv.z * cv.z + (double)zv.w * cv.w;
            }
            #pragma unroll
            for (int off = 1; off < 32; off <<= 1) acc += __shfl_xor(acc, off, 32);
            double sc = c2d[ci] - 2.0 * acc;
            double so = __shfl_xor(sc, 32, 64);
            int    io = __shfl_xor(ci, 32, 64);
            double s0 = h ? so : sc;  int i0 = h ? io : ci;   // cand 2p
            double s1 = h ? sc : so;  int i1 = h ? ci : io;   // cand 2p+1
            if (s0 < bs || (s0 == bs && i0 < bi)) { bs = s0; bi = i0; }
            if (s1 < bs || (s1 == bs && i1 < bi)) { bs = s1; bi = i1; }
        }
        if (lane == 0) {
            bidx[wv * 4 + rr] = bi;
            out[(size_t)NZQ + 1 + n] = (float)bi;   // indices output
        }
    }
    __syncthreads();

    // phase 2: gather + squared-error partial + stage for transposed write
    float accl = 0.f;
    for (int l = 0; l < 16; ++l) {
        int n = n0 + l;
        int bi = bidx[l];
        float zq = cb[(size_t)bi * K_ + tid];
        float d  = zf[(size_t)n * K_ + tid] - zq;
        accl += d * d;
        tile[l][tid] = zq;
    }
    #pragma unroll
    for (int off = 32; off; off >>= 1) accl += __shfl_down(accl, off, 64);
    if ((tid & 63) == 0) wsum[tid >> 6] = accl;
    __syncthreads();
    if (tid == 0) partials[blockIdx.x] = wsum[0] + wsum[1] + wsum[2] + wsum[3];
    // transposed write: out[(b*C + c)*HW + hw0 + l]
    int b = n0 >> 10, hw0 = n0 & 1023;
    #pragma unroll
    for (int g = 0; g < 4; ++g) {
        float4 v = make_float4(tile[g * 4 + 0][tid], tile[g * 4 + 1][tid],
                               tile[g * 4 + 2][tid], tile[g * 4 + 3][tid]);
        *(float4*)&out[((size_t)b * C_ + tid) * HW_ + hw0 + g * 4] = v;
    }
}

// ---------------------------------------------------------------------------
// E: loss = 1.25 * sum(partials) / (N*C)
__global__ void k_loss(const float* __restrict__ partials, float* __restrict__ out) {
    __shared__ double ws4[4];
    int tid = threadIdx.x;
    double s = 0.0;
    for (int i = tid; i < 1024; i += 256) s += (double)partials[i];
    #pragma unroll
    for (int off = 32; off; off >>= 1) s += __shfl_down(s, off, 64);
    if ((tid & 63) == 0) ws4[tid >> 6] = s;
    __syncthreads();
    if (tid == 0) {
        double tot = ws4[0] + ws4[1] + ws4[2] + ws4[3];
        out[NZQ] = (float)(1.25 * tot / (double)NZQ);
    }
}

// ---------------------------------------------------------------------------
extern "C" void kernel_launch(void* const* d_in, const int* in_sizes, int n_in,
                              void* d_out, int out_size, void* d_ws, size_t ws_size,
                              hipStream_t stream) {
    const float* z  = (const float*)d_in[0];
    const float* fc = (const float*)d_in[1];
    const float* wt = (const float*)d_in[2];
    float* out = (float*)d_out;

    float* ws = (float*)d_ws;
    const size_t OFF_ZF   = 0;                                   // N*K f
    const size_t OFF_CB   = OFF_ZF + (size_t)N_ * K_;            // NE*K f
    const size_t OFF_C2   = OFF_CB + (size_t)NE_ * K_;           // NE f
    const size_t OFF_C2D  = OFF_C2 + NE_;                        // NE d (2 f each)
    const size_t OFF_T2I  = OFF_C2D + (size_t)NE_ * 2;           // NSPLIT*N*2 i
    const size_t OFF_PART = OFF_T2I + (size_t)NSPLIT * N_ * 2;   // 1024 f
    const size_t OFF_ZH   = OFF_PART + 1024;                     // fp16 N*K
    const size_t OFF_CBH  = OFF_ZH + (size_t)N_ * K_ / 2;        // fp16 NE*K

    float*  zf   = ws + OFF_ZF;
    float*  cb   = ws + OFF_CB;
    float*  c2   = ws + OFF_C2;
    double* c2d  = (double*)(ws + OFF_C2D);
    int*    t2i  = (int*)(ws + OFF_T2I);
    float*  part = ws + OFF_PART;
    u16*    zh   = (u16*)(ws + OFF_ZH);
    u16*    cbh  = (u16*)(ws + OFF_CBH);

    k_transpose_z<<<dim3(HW_ / 32, C_ / 32, B_), dim3(32, 8), 0, stream>>>(z, zf, zh);
    k_codebook_gemm<<<dim3(NE_ / 64, K_ / 64), 256, 0, stream>>>(fc, wt, cb, cbh);
    k_c2<<<NE_ / 4, 256, 0, stream>>>(cb, c2, c2d);
    k_scan_mfma<<<dim3(N_ / 128, NSPLIT), 256, 0, stream>>>(zh, cbh, c2, t2i);
    k_finalize<<<N_ / 16, 256, 0, stream>>>(zf, cb, c2d, t2i, out, part);
    k_loss<<<1, 256, 0, stream>>>(part, out);
}